// Round 2
// baseline (1110.671 us; speedup 1.0000x reference)
//
#include <hip/hip_runtime.h>

// NeRF positional encoding:
// out[n, 0:3]               = coords[n, 0:3]
// out[n, 3 + (i*3+j)*2 + s] = s==0 ? sin(2^i * pi * c_j) : cos(2^i * pi * c_j)
// PER_POINT = 3 + 10*3*2 = 63 floats.
//
// Strategy: flat output-major indexing. Each thread produces 4 consecutive
// flat output floats and stores one aligned 16B vector (coalesced, the
// 16B/lane sweet spot). sin/cos via hw v_sin_f32 (revolutions) with exact
// pow2-scale + fract range reduction; cos folded in as sin(x + 0.25 rev).

typedef float v4f __attribute__((ext_vector_type(4)));  // native vec for nontemporal store

__global__ __launch_bounds__(256) void PosEncoding_kernel(
    const float* __restrict__ coords,
    float* __restrict__ out,
    unsigned n4)
{
    unsigned t = blockIdx.x * 256u + threadIdx.x;
    if (t >= n4) return;
    unsigned base = t * 4u;

    float v[4];
#pragma unroll
    for (int u = 0; u < 4; ++u) {
        unsigned idx = base + (unsigned)u;
        // n = idx / 63, r = idx % 63  (compiler emits magic-mul)
        unsigned n = idx / 63u;
        unsigned r = idx - n * 63u;

        bool copy = r < 3u;              // first 3 outputs are raw coords
        unsigned k  = r - 3u;            // garbage when copy (discarded)
        unsigned i  = k / 6u;            // frequency index 0..9
        unsigned rem = k - i * 6u;       // 0..5
        unsigned j  = rem >> 1;          // dim 0..2
        unsigned s  = rem & 1u;          // 0=sin, 1=cos

        unsigned jj = copy ? r : j;
        float c = coords[n * 3u + jj];

        // scale = 2^(i-1): sin(2^i*pi*c) = sin(2*pi * (2^(i-1)*c))
        unsigned iexp = copy ? 0u : i;   // keep exponent sane on copy lanes
        float scale = __uint_as_float((126u + iexp) << 23);

        float rev = c * scale;                       // exact (pow2 mul)
        rev = __builtin_amdgcn_fractf(rev);          // exact reduction -> [0,1)
        rev = rev + (s ? 0.25f : 0.0f);              // cos = sin shifted 1/4 rev
        rev = __builtin_amdgcn_fractf(rev);          // back to [0,1)
        float sv = __builtin_amdgcn_sinf(rev);       // v_sin_f32: sin(2*pi*rev)

        v[u] = copy ? c : sv;
    }

    v4f o = { v[0], v[1], v[2], v[3] };
    __builtin_nontemporal_store(o, (v4f*)(out + base));
}

extern "C" void kernel_launch(void* const* d_in, const int* in_sizes, int n_in,
                              void* d_out, int out_size, void* d_ws, size_t ws_size,
                              hipStream_t stream) {
    const float* coords = (const float*)d_in[0];
    float* out = (float*)d_out;

    // out_size = 4194304 * 63 = 264,241,152 — divisible by 4.
    unsigned n4 = (unsigned)(out_size / 4);
    unsigned blocks = (n4 + 255u) / 256u;
    PosEncoding_kernel<<<blocks, 256, 0, stream>>>(coords, out, n4);
}